// Round 6
// baseline (392.856 us; speedup 1.0000x reference)
//
#include <hip/hip_runtime.h>

#define EMBED 1024
#define NHEADS 16
#define HDIM 64
#define SEQ 2048
#define BATCH 2
#define MROWS (BATCH * SEQ)   // 4096

using bf16x8 = __attribute__((ext_vector_type(8))) short;
using f32x4  = __attribute__((ext_vector_type(4))) float;
using us4    = __attribute__((ext_vector_type(4))) unsigned short;

__device__ __forceinline__ unsigned short f2bf(float f) {
    unsigned int u = __builtin_bit_cast(unsigned int, f);
    u = (u + 0x7fffu + ((u >> 16) & 1u)) >> 16;   // RNE
    return (unsigned short)u;
}

__device__ __forceinline__ void async16(const unsigned short* g, unsigned short* l) {
    __builtin_amdgcn_global_load_lds(
        (const __attribute__((address_space(1))) void*)g,
        (__attribute__((address_space(3))) void*)l, 16, 0, 0);
}

// ---------------------------------------------------------------------------
// convert x (fp32 [4096][1024]) -> bf16, 4 elems/thread
// ---------------------------------------------------------------------------
__global__ __launch_bounds__(256)
void cvt_x(const float* __restrict__ in, unsigned short* __restrict__ out)
{
    int i = blockIdx.x * 256 + threadIdx.x;
    float4 v = ((const float4*)in)[i];
    us4 o;
    o[0] = f2bf(v.x); o[1] = f2bf(v.y); o[2] = f2bf(v.z); o[3] = f2bf(v.w);
    ((us4*)out)[i] = o;
}

// ---------------------------------------------------------------------------
// convert + transpose weights: W fp32 [k][n] -> Wt bf16 [n][k]. 64x64 tiles.
// ---------------------------------------------------------------------------
__global__ __launch_bounds__(256)
void cvt_w(const float* __restrict__ W0, const float* __restrict__ W1,
           const float* __restrict__ W2, const float* __restrict__ W3,
           unsigned short* __restrict__ T0, unsigned short* __restrict__ T1,
           unsigned short* __restrict__ T2, unsigned short* __restrict__ T3)
{
    const float* W = blockIdx.z == 0 ? W0 : blockIdx.z == 1 ? W1 :
                     blockIdx.z == 2 ? W2 : W3;
    unsigned short* T = blockIdx.z == 0 ? T0 : blockIdx.z == 1 ? T1 :
                        blockIdx.z == 2 ? T2 : T3;
    __shared__ unsigned short tile[64][72];
    const int tid = threadIdx.x;
    const int k0 = blockIdx.y << 6, n0 = blockIdx.x << 6;
    const int lr = tid >> 4, lc = (tid & 15) << 2;
#pragma unroll
    for (int it = 0; it < 4; ++it) {
        int kr = lr + it * 16;
        float4 v = *(const float4*)(W + (size_t)(k0 + kr) * EMBED + n0 + lc);
        tile[lc + 0][kr] = f2bf(v.x);
        tile[lc + 1][kr] = f2bf(v.y);
        tile[lc + 2][kr] = f2bf(v.z);
        tile[lc + 3][kr] = f2bf(v.w);
    }
    __syncthreads();
#pragma unroll
    for (int it = 0; it < 4; ++it) {
        int nr = lr + it * 16;
        us4 o = *(const us4*)(&tile[nr][lc]);
        *(us4*)(T + (size_t)(n0 + nr) * EMBED + k0 + lc) = o;
    }
}

// ---------------------------------------------------------------------------
// MFMA GEMM core 128x128 (unchanged)
// ---------------------------------------------------------------------------
__device__ __forceinline__ void mfma_gemm_core(
    const unsigned short* __restrict__ A, const unsigned short* __restrict__ Bt,
    int bm, int n0, unsigned short* As, unsigned short* Bs,
    int wv, int lane, f32x4 acc[4][4])
{
    const int m16 = lane & 15, quad = lane >> 4;
    const int mb = (wv >> 1) << 6;
    const int nb = (wv & 1) << 6;

    const unsigned short* ga = A  + (size_t)(bm + wv * 32 + (lane >> 3)) * EMBED + ((lane & 7) << 3);
    const unsigned short* gb = Bt + (size_t)(n0 + wv * 32 + (lane >> 3)) * EMBED + ((lane & 7) << 3);
    unsigned short* la = As + wv * 32 * 64;
    unsigned short* lb = Bs + wv * 32 * 64;

    for (int k0 = 0; k0 < EMBED; k0 += 64) {
        __syncthreads();
#pragma unroll
        for (int j = 0; j < 4; ++j) {
            async16(ga + j * 8 * EMBED, la + j * 8 * 64);
            async16(gb + j * 8 * EMBED, lb + j * 8 * 64);
        }
        ga += 64; gb += 64;
        __syncthreads();
#pragma unroll
        for (int ks = 0; ks < 2; ++ks) {
            const int ko = ks * 32 + (quad << 3);
            bf16x8 af[4], bfv[4];
#pragma unroll
            for (int i = 0; i < 4; ++i) {
                af[i]  = *(const bf16x8*)(As + (mb + i * 16 + m16) * 64 + ko);
                bfv[i] = *(const bf16x8*)(Bs + (nb + i * 16 + m16) * 64 + ko);
            }
#pragma unroll
            for (int i = 0; i < 4; ++i)
#pragma unroll
                for (int j = 0; j < 4; ++j)
                    acc[i][j] = __builtin_amdgcn_mfma_f32_16x16x32_bf16(
                        af[i], bfv[j], acc[i][j], 0, 0, 0);
        }
    }
}

// ---------------------------------------------------------------------------
// MFMA GEMM core 128x64 (for out_gemm)
// ---------------------------------------------------------------------------
__device__ __forceinline__ void mfma_gemm_core64(
    const unsigned short* __restrict__ A, const unsigned short* __restrict__ Bt,
    int bm, int n0, unsigned short* As, unsigned short* Bs,
    int wv, int lane, f32x4 acc[4][2])
{
    const int m16 = lane & 15, quad = lane >> 4;
    const int mb = (wv >> 1) << 6;
    const int nb = (wv & 1) << 5;

    const unsigned short* ga = A  + (size_t)(bm + wv * 32 + (lane >> 3)) * EMBED + ((lane & 7) << 3);
    const unsigned short* gb = Bt + (size_t)(n0 + wv * 16 + (lane >> 3)) * EMBED + ((lane & 7) << 3);
    unsigned short* la = As + wv * 32 * 64;
    unsigned short* lb = Bs + wv * 16 * 64;

    for (int k0 = 0; k0 < EMBED; k0 += 64) {
        __syncthreads();
#pragma unroll
        for (int j = 0; j < 4; ++j)
            async16(ga + j * 8 * EMBED, la + j * 8 * 64);
#pragma unroll
        for (int j = 0; j < 2; ++j)
            async16(gb + j * 8 * EMBED, lb + j * 8 * 64);
        ga += 64; gb += 64;
        __syncthreads();
#pragma unroll
        for (int ks = 0; ks < 2; ++ks) {
            const int ko = ks * 32 + (quad << 3);
            bf16x8 af[4], bfv[2];
#pragma unroll
            for (int i = 0; i < 4; ++i)
                af[i] = *(const bf16x8*)(As + (mb + i * 16 + m16) * 64 + ko);
#pragma unroll
            for (int j = 0; j < 2; ++j)
                bfv[j] = *(const bf16x8*)(Bs + (nb + j * 16 + m16) * 64 + ko);
#pragma unroll
            for (int i = 0; i < 4; ++i)
#pragma unroll
                for (int j = 0; j < 2; ++j)
                    acc[i][j] = __builtin_amdgcn_mfma_f32_16x16x32_bf16(
                        af[i], bfv[j], acc[i][j], 0, 0, 0);
        }
    }
}

// ---------------------------------------------------------------------------
// Fused QKV projection (unchanged)
// ---------------------------------------------------------------------------
__global__ __launch_bounds__(256)
void qkv_gemm(const unsigned short* __restrict__ xb,
              const unsigned short* __restrict__ Wtq,
              const unsigned short* __restrict__ Wtk,
              const unsigned short* __restrict__ Wtv,
              const float* __restrict__ bq, const float* __restrict__ bk,
              const float* __restrict__ bv,
              unsigned short* __restrict__ Qo, unsigned short* __restrict__ Ko,
              unsigned short* __restrict__ Vto)
{
    __shared__ __align__(16) unsigned short As[128 * 64];
    __shared__ __align__(16) unsigned short Bs[128 * 64];
    const int tid = threadIdx.x, wv = tid >> 6, lane = tid & 63;
    const int m16 = lane & 15, quad = lane >> 4;
    const int which = blockIdx.x >> 3;
    const int n0 = (blockIdx.x & 7) << 7;
    const int bm = blockIdx.y << 7;
    const unsigned short* Bt = which == 0 ? Wtq : which == 1 ? Wtk : Wtv;
    const float* bias = which == 0 ? bq : which == 1 ? bk : bv;

    f32x4 acc[4][4];
#pragma unroll
    for (int i = 0; i < 4; ++i)
#pragma unroll
        for (int j = 0; j < 4; ++j) acc[i][j] = (f32x4){0.f, 0.f, 0.f, 0.f};

    mfma_gemm_core(xb, Bt, bm, n0, As, Bs, wv, lane, acc);

    const int mb = (wv >> 1) << 6, nb = (wv & 1) << 6;
    const float qscale = 0.125f * 1.4426950408889634f;
#pragma unroll
    for (int i = 0; i < 4; ++i) {
        const int m0 = bm + mb + i * 16 + quad * 4;
        const int b = m0 >> 11, t0 = m0 & (SEQ - 1);
#pragma unroll
        for (int j = 0; j < 4; ++j) {
            const int n = n0 + nb + j * 16 + m16;
            const int h = n >> 6, d = n & 63;
            const float bval = bias[n];
            if (which == 2) {
                us4 v;
#pragma unroll
                for (int r = 0; r < 4; ++r) v[r] = f2bf(acc[i][j][r] + bval);
                *(us4*)(Vto + ((((size_t)(b * NHEADS + h)) << 6) + d) * SEQ + t0) = v;
            } else {
                const float sc = which == 0 ? qscale : 1.f;
                unsigned short* dst = (which == 0 ? Qo : Ko) +
                    ((((size_t)(b * NHEADS + h)) << 11) + t0) * 64 + d;
#pragma unroll
                for (int r = 0; r < 4; ++r)
                    dst[(size_t)r * 64] = f2bf((acc[i][j][r] + bval) * sc);
            }
        }
    }
}

// ---------------------------------------------------------------------------
// Output projection: out fp32 = ao_bf16 @ Wo + bo. 128x64 tile.
// ---------------------------------------------------------------------------
__global__ __launch_bounds__(256)
void out_gemm(const unsigned short* __restrict__ aob,
              const unsigned short* __restrict__ Wto,
              const float* __restrict__ bo, float* __restrict__ out)
{
    __shared__ __align__(16) unsigned short As[128 * 64];
    __shared__ __align__(16) unsigned short Bs[64 * 64];
    const int tid = threadIdx.x, wv = tid >> 6, lane = tid & 63;
    const int m16 = lane & 15, quad = lane >> 4;
    const int n0 = blockIdx.x << 6;
    const int bm = blockIdx.y << 7;

    f32x4 acc[4][2];
#pragma unroll
    for (int i = 0; i < 4; ++i)
#pragma unroll
        for (int j = 0; j < 2; ++j) acc[i][j] = (f32x4){0.f, 0.f, 0.f, 0.f};

    mfma_gemm_core64(aob, Wto, bm, n0, As, Bs, wv, lane, acc);

    const int mb = (wv >> 1) << 6, nb = (wv & 1) << 5;
#pragma unroll
    for (int i = 0; i < 4; ++i) {
        const int m0 = bm + mb + i * 16 + quad * 4;
#pragma unroll
        for (int j = 0; j < 2; ++j) {
            const int n = n0 + nb + j * 16 + m16;
            const float bval = bo[n];
#pragma unroll
            for (int r = 0; r < 4; ++r)
                out[(size_t)(m0 + r) * EMBED + n] = acc[i][j][r] + bval;
        }
    }
}

// ---------------------------------------------------------------------------
// Wave-per-block MFMA flash attention (operand-swapped), K/V fragments
// loaded DIRECTLY from global (16B contiguous, L1/L2-served).
// One block = one wave = 16 queries (t = qs*16 + m16) of one (b,h).
// P handoff through 2.25KB LDS using ROUND-4-PROVEN types (f2bf + us4
// stores, bf16x8 reads) + a single-wave __syncthreads() (lowers to a
// lgkmcnt wait) between write and read to kill any aliasing/ordering
// hazard. Grid 128x32 = 4096 blocks, heavy-first (qs = 127-bx).
// ---------------------------------------------------------------------------
__global__ __launch_bounds__(64)
void attn_mfma(const unsigned short* __restrict__ Qb,
               const unsigned short* __restrict__ Kb,
               const unsigned short* __restrict__ Vtb,
               unsigned short* __restrict__ Oout)
{
    __shared__ __align__(16) unsigned short Ps[16 * 72];

    const int lane = threadIdx.x;
    const int m16  = lane & 15;
    const int quad = lane >> 4;
    const int bh   = blockIdx.y;
    const int b    = bh >> 4, h = bh & 15;
    const int qs   = 127 - (int)blockIdx.x;   // heavy blocks dispatch first
    const int qmod = qs & 3;
    const int nkt  = qs >> 2;                 // diagonal key-tile index

    // Q fragment (B operand): n = query = m16, k = d = quad*8+j
    const unsigned short* qp =
        Qb + (((size_t)bh << 11) + (qs << 4) + m16) * 64 + (quad << 3);
    bf16x8 qa0 = *(const bf16x8*)qp;
    bf16x8 qa1 = *(const bf16x8*)(qp + 32);

    const unsigned short* Kbase = Kb + (((size_t)bh << 11) << 6);   // [t][d]
    const unsigned short* Vbase = Vtb + (((size_t)bh << 6) << 11);  // [d][t]

    f32x4 o[4];
#pragma unroll
    for (int dt = 0; dt < 4; ++dt) o[dt] = (f32x4){0.f, 0.f, 0.f, 0.f};
    float m_ = -1e30f, l_ = 0.f;

    for (int kt = 0; kt <= nkt; ++kt) {
        const int k0 = kt << 6;
        const bool diag = (kt == nkt);

        // S^T = K·Q^T: s[g][r] = score(key k0+g*16+quad*4+r, query m16)
        f32x4 s[4];
#pragma unroll
        for (int g = 0; g < 4; ++g) {
            if (diag && g > qmod) {
                s[g] = (f32x4){-1e30f, -1e30f, -1e30f, -1e30f};
                continue;
            }
            const unsigned short* kp =
                Kbase + (size_t)(k0 + g * 16 + m16) * 64 + (quad << 3);
            bf16x8 kb0 = *(const bf16x8*)kp;
            bf16x8 kb1 = *(const bf16x8*)(kp + 32);
            s[g] = (f32x4){0.f, 0.f, 0.f, 0.f};
            s[g] = __builtin_amdgcn_mfma_f32_16x16x32_bf16(kb0, qa0, s[g], 0, 0, 0);
            s[g] = __builtin_amdgcn_mfma_f32_16x16x32_bf16(kb1, qa1, s[g], 0, 0, 0);
        }
        if (diag) {   // partial mask on group g == qmod
#pragma unroll
            for (int r = 0; r < 4; ++r)
                if (quad * 4 + r > m16) s[qmod][r] = -1e30f;
        }

        // max: pairwise tree + 2 cross-quad shuffles
        f32x4 t01, t23, tm;
#pragma unroll
        for (int r = 0; r < 4; ++r) {
            t01[r] = fmaxf(s[0][r], s[1][r]);
            t23[r] = fmaxf(s[2][r], s[3][r]);
            tm[r]  = fmaxf(t01[r], t23[r]);
        }
        float mx = fmaxf(fmaxf(tm[0], tm[1]), fmaxf(tm[2], tm[3]));
        mx = fmaxf(mx, __shfl_xor(mx, 16));
        mx = fmaxf(mx, __shfl_xor(mx, 32));
        const float nm = fmaxf(m_, mx);
        const float alpha = exp2f(m_ - nm);

#pragma unroll
        for (int g = 0; g < 4; ++g)
#pragma unroll
            for (int r = 0; r < 4; ++r) s[g][r] = exp2f(s[g][r] - nm);

        f32x4 a01, a23, at;
#pragma unroll
        for (int r = 0; r < 4; ++r) {
            a01[r] = s[0][r] + s[1][r];
            a23[r] = s[2][r] + s[3][r];
            at[r]  = a01[r] + a23[r];
        }
        float sum = (at[0] + at[1]) + (at[2] + at[3]);
        sum += __shfl_xor(sum, 16);
        sum += __shfl_xor(sum, 32);
        l_ = l_ * alpha + sum;
        m_ = nm;

        // P -> LDS bf16, ROUND-4-PROVEN path: f2bf + us4 stores
#pragma unroll
        for (int g = 0; g < 4; ++g) {
            us4 pv;
#pragma unroll
            for (int r = 0; r < 4; ++r) pv[r] = f2bf(s[g][r]);
            *(us4*)(&Ps[m16 * 72 + g * 16 + quad * 4]) = pv;
        }
        __syncthreads();   // single-wave: lowers to lgkmcnt wait; orders P write->read

#pragma unroll
        for (int dt = 0; dt < 4; ++dt) o[dt] *= alpha;

        // O^T += V^T·P^T  (A = V^T frag from global, B = P^T frag from LDS)
        const unsigned short* pp = Ps + m16 * 72 + (quad << 3);
        bf16x8 pa0 = *(const bf16x8*)pp;
        bf16x8 pa1 = *(const bf16x8*)(pp + 32);
        const bool skip_hi = diag && (qmod < 2);   // keys 32..63 all masked
#pragma unroll
        for (int dt = 0; dt < 4; ++dt) {
            const unsigned short* vp =
                Vbase + (size_t)(dt * 16 + m16) * SEQ + k0 + (quad << 3);
            bf16x8 vb0 = *(const bf16x8*)vp;
            o[dt] = __builtin_amdgcn_mfma_f32_16x16x32_bf16(vb0, pa0, o[dt], 0, 0, 0);
            if (!skip_hi) {
                bf16x8 vb1 = *(const bf16x8*)(vp + 32);
                o[dt] = __builtin_amdgcn_mfma_f32_16x16x32_bf16(vb1, pa1, o[dt], 0, 0, 0);
            }
        }
        __syncthreads();   // order P read of iter kt before P write of kt+1
    }

    // epilogue: lane m16 = query t, holds d = dt*16 + quad*4 + r
    const float inv = 1.f / l_;
    const int t = (qs << 4) + m16;
    unsigned short* dst =
        Oout + ((size_t)((b << 11) + t) << 10) + (h << 6) + (quad << 2);
#pragma unroll
    for (int dt = 0; dt < 4; ++dt) {
        us4 w;
#pragma unroll
        for (int r = 0; r < 4; ++r) w[r] = f2bf(o[dt][r] * inv);
        *(us4*)(dst + dt * 16) = w;
    }
}

extern "C" void kernel_launch(void* const* d_in, const int* in_sizes, int n_in,
                              void* d_out, int out_size, void* d_ws, size_t ws_size,
                              hipStream_t stream) {
    const float* x  = (const float*)d_in[0];
    const float* Wq = (const float*)d_in[1];
    const float* bq = (const float*)d_in[2];
    const float* Wk = (const float*)d_in[3];
    const float* bk = (const float*)d_in[4];
    const float* Wv = (const float*)d_in[5];
    const float* bv = (const float*)d_in[6];
    const float* Wo = (const float*)d_in[7];
    const float* bo = (const float*)d_in[8];
    float* out = (float*)d_out;

    const size_t HSZ = (size_t)MROWS * EMBED;   // 4M elems
    const size_t WSZ = (size_t)EMBED * EMBED;   // 1M elems
    unsigned short* qb  = (unsigned short*)d_ws;
    unsigned short* kb  = qb + HSZ;
    unsigned short* vtb = kb + HSZ;
    unsigned short* aob = vtb + HSZ;
    unsigned short* xb  = aob + HSZ;
    unsigned short* wtq = xb + HSZ;
    unsigned short* wtk = wtq + WSZ;
    unsigned short* wtv = wtk + WSZ;
    unsigned short* wto = wtv + WSZ;

    cvt_x<<<MROWS * EMBED / 1024, 256, 0, stream>>>(x, xb);
    cvt_w<<<dim3(16, 16, 4), 256, 0, stream>>>(Wq, Wk, Wv, Wo, wtq, wtk, wtv, wto);

    qkv_gemm<<<dim3(24, 32), 256, 0, stream>>>(xb, wtq, wtk, wtv, bq, bk, bv,
                                               qb, kb, vtb);

    attn_mfma<<<dim3(128, BATCH * NHEADS), 64, 0, stream>>>(qb, kb, vtb, aob);

    out_gemm<<<dim3(16, 32), 256, 0, stream>>>(aob, wto, bo, out);
}

// Round 7
// 293.499 us; speedup vs baseline: 1.3385x; 1.3385x over previous
//
#include <hip/hip_runtime.h>

#define EMBED 1024
#define NHEADS 16
#define HDIM 64
#define SEQ 2048
#define BATCH 2
#define MROWS (BATCH * SEQ)   // 4096

using bf16x8 = __attribute__((ext_vector_type(8))) short;
using f32x4  = __attribute__((ext_vector_type(4))) float;
using us4    = __attribute__((ext_vector_type(4))) unsigned short;

__device__ __forceinline__ unsigned short f2bf(float f) {
    unsigned int u = __builtin_bit_cast(unsigned int, f);
    u = (u + 0x7fffu + ((u >> 16) & 1u)) >> 16;   // RNE
    return (unsigned short)u;
}

__device__ __forceinline__ void async16(const unsigned short* g, unsigned short* l) {
    __builtin_amdgcn_global_load_lds(
        (const __attribute__((address_space(1))) void*)g,
        (__attribute__((address_space(3))) void*)l, 16, 0, 0);
}

// ---------------------------------------------------------------------------
// Merged conversion kernel. grid (1024, 1, 5).
// z==0: x fp32 -> bf16 (blocks 0..1023, 4 float4/thread)
// z==1..4: W{q,k,v,o} fp32 [k][n] -> bf16 [n][k] transpose (blocks 0..255)
// ---------------------------------------------------------------------------
__global__ __launch_bounds__(256)
void cvt_all(const float* __restrict__ x,
             const float* __restrict__ W1, const float* __restrict__ W2,
             const float* __restrict__ W3, const float* __restrict__ W4,
             unsigned short* __restrict__ xb,
             unsigned short* __restrict__ T1, unsigned short* __restrict__ T2,
             unsigned short* __restrict__ T3, unsigned short* __restrict__ T4)
{
    const int tid = threadIdx.x;
    const int z = blockIdx.z;
    if (z == 0) {
        // 1M float4 total: 1024 blocks x 256 thr x 4
        int base = blockIdx.x * 1024 + tid;
#pragma unroll
        for (int j = 0; j < 4; ++j) {
            int i = base + j * 256;
            float4 v = ((const float4*)x)[i];
            us4 o;
            o[0] = f2bf(v.x); o[1] = f2bf(v.y); o[2] = f2bf(v.z); o[3] = f2bf(v.w);
            ((us4*)xb)[i] = o;
        }
        return;
    }
    if (blockIdx.x >= 256) return;
    const float* W = z == 1 ? W1 : z == 2 ? W2 : z == 3 ? W3 : W4;
    unsigned short* T = z == 1 ? T1 : z == 2 ? T2 : z == 3 ? T3 : T4;
    __shared__ unsigned short tile[64][72];
    const int k0 = (blockIdx.x >> 4) << 6, n0 = (blockIdx.x & 15) << 6;
    const int lr = tid >> 4, lc = (tid & 15) << 2;
#pragma unroll
    for (int it = 0; it < 4; ++it) {
        int kr = lr + it * 16;
        float4 v = *(const float4*)(W + (size_t)(k0 + kr) * EMBED + n0 + lc);
        tile[lc + 0][kr] = f2bf(v.x);
        tile[lc + 1][kr] = f2bf(v.y);
        tile[lc + 2][kr] = f2bf(v.z);
        tile[lc + 3][kr] = f2bf(v.w);
    }
    __syncthreads();
#pragma unroll
    for (int it = 0; it < 4; ++it) {
        int nr = lr + it * 16;
        us4 o = *(const us4*)(&tile[nr][lc]);
        *(us4*)(T + (size_t)(n0 + nr) * EMBED + k0 + lc) = o;
    }
}

// ---------------------------------------------------------------------------
// MFMA GEMM core 128x128 (proven, unchanged)
// ---------------------------------------------------------------------------
__device__ __forceinline__ void mfma_gemm_core(
    const unsigned short* __restrict__ A, const unsigned short* __restrict__ Bt,
    int bm, int n0, unsigned short* As, unsigned short* Bs,
    int wv, int lane, f32x4 acc[4][4])
{
    const int m16 = lane & 15, quad = lane >> 4;
    const int mb = (wv >> 1) << 6;
    const int nb = (wv & 1) << 6;

    const unsigned short* ga = A  + (size_t)(bm + wv * 32 + (lane >> 3)) * EMBED + ((lane & 7) << 3);
    const unsigned short* gb = Bt + (size_t)(n0 + wv * 32 + (lane >> 3)) * EMBED + ((lane & 7) << 3);
    unsigned short* la = As + wv * 32 * 64;
    unsigned short* lb = Bs + wv * 32 * 64;

    for (int k0 = 0; k0 < EMBED; k0 += 64) {
        __syncthreads();
#pragma unroll
        for (int j = 0; j < 4; ++j) {
            async16(ga + j * 8 * EMBED, la + j * 8 * 64);
            async16(gb + j * 8 * EMBED, lb + j * 8 * 64);
        }
        ga += 64; gb += 64;
        __syncthreads();
#pragma unroll
        for (int ks = 0; ks < 2; ++ks) {
            const int ko = ks * 32 + (quad << 3);
            bf16x8 af[4], bfv[4];
#pragma unroll
            for (int i = 0; i < 4; ++i) {
                af[i]  = *(const bf16x8*)(As + (mb + i * 16 + m16) * 64 + ko);
                bfv[i] = *(const bf16x8*)(Bs + (nb + i * 16 + m16) * 64 + ko);
            }
#pragma unroll
            for (int i = 0; i < 4; ++i)
#pragma unroll
                for (int j = 0; j < 4; ++j)
                    acc[i][j] = __builtin_amdgcn_mfma_f32_16x16x32_bf16(
                        af[i], bfv[j], acc[i][j], 0, 0, 0);
        }
    }
}

// ---------------------------------------------------------------------------
// MFMA GEMM core 128x64 (proven, unchanged)
// ---------------------------------------------------------------------------
__device__ __forceinline__ void mfma_gemm_core64(
    const unsigned short* __restrict__ A, const unsigned short* __restrict__ Bt,
    int bm, int n0, unsigned short* As, unsigned short* Bs,
    int wv, int lane, f32x4 acc[4][2])
{
    const int m16 = lane & 15, quad = lane >> 4;
    const int mb = (wv >> 1) << 6;
    const int nb = (wv & 1) << 5;

    const unsigned short* ga = A  + (size_t)(bm + wv * 32 + (lane >> 3)) * EMBED + ((lane & 7) << 3);
    const unsigned short* gb = Bt + (size_t)(n0 + wv * 16 + (lane >> 3)) * EMBED + ((lane & 7) << 3);
    unsigned short* la = As + wv * 32 * 64;
    unsigned short* lb = Bs + wv * 16 * 64;

    for (int k0 = 0; k0 < EMBED; k0 += 64) {
        __syncthreads();
#pragma unroll
        for (int j = 0; j < 4; ++j)
            async16(ga + j * 8 * EMBED, la + j * 8 * 64);
#pragma unroll
        for (int j = 0; j < 2; ++j)
            async16(gb + j * 8 * EMBED, lb + j * 8 * 64);
        ga += 64; gb += 64;
        __syncthreads();
#pragma unroll
        for (int ks = 0; ks < 2; ++ks) {
            const int ko = ks * 32 + (quad << 3);
            bf16x8 af[4], bfv[2];
#pragma unroll
            for (int i = 0; i < 4; ++i)
                af[i] = *(const bf16x8*)(As + (mb + i * 16 + m16) * 64 + ko);
#pragma unroll
            for (int j = 0; j < 2; ++j)
                bfv[j] = *(const bf16x8*)(Bs + (nb + j * 16 + m16) * 64 + ko);
#pragma unroll
            for (int i = 0; i < 4; ++i)
#pragma unroll
                for (int j = 0; j < 2; ++j)
                    acc[i][j] = __builtin_amdgcn_mfma_f32_16x16x32_bf16(
                        af[i], bfv[j], acc[i][j], 0, 0, 0);
        }
    }
}

// ---------------------------------------------------------------------------
// Fused QKV projection (proven, unchanged)
// ---------------------------------------------------------------------------
__global__ __launch_bounds__(256)
void qkv_gemm(const unsigned short* __restrict__ xb,
              const unsigned short* __restrict__ Wtq,
              const unsigned short* __restrict__ Wtk,
              const unsigned short* __restrict__ Wtv,
              const float* __restrict__ bq, const float* __restrict__ bk,
              const float* __restrict__ bv,
              unsigned short* __restrict__ Qo, unsigned short* __restrict__ Ko,
              unsigned short* __restrict__ Vto)
{
    __shared__ __align__(16) unsigned short As[128 * 64];
    __shared__ __align__(16) unsigned short Bs[128 * 64];
    const int tid = threadIdx.x, wv = tid >> 6, lane = tid & 63;
    const int m16 = lane & 15, quad = lane >> 4;
    const int which = blockIdx.x >> 3;
    const int n0 = (blockIdx.x & 7) << 7;
    const int bm = blockIdx.y << 7;
    const unsigned short* Bt = which == 0 ? Wtq : which == 1 ? Wtk : Wtv;
    const float* bias = which == 0 ? bq : which == 1 ? bk : bv;

    f32x4 acc[4][4];
#pragma unroll
    for (int i = 0; i < 4; ++i)
#pragma unroll
        for (int j = 0; j < 4; ++j) acc[i][j] = (f32x4){0.f, 0.f, 0.f, 0.f};

    mfma_gemm_core(xb, Bt, bm, n0, As, Bs, wv, lane, acc);

    const int mb = (wv >> 1) << 6, nb = (wv & 1) << 6;
    const float qscale = 0.125f * 1.4426950408889634f;
#pragma unroll
    for (int i = 0; i < 4; ++i) {
        const int m0 = bm + mb + i * 16 + quad * 4;
        const int b = m0 >> 11, t0 = m0 & (SEQ - 1);
#pragma unroll
        for (int j = 0; j < 4; ++j) {
            const int n = n0 + nb + j * 16 + m16;
            const int h = n >> 6, d = n & 63;
            const float bval = bias[n];
            if (which == 2) {
                us4 v;
#pragma unroll
                for (int r = 0; r < 4; ++r) v[r] = f2bf(acc[i][j][r] + bval);
                *(us4*)(Vto + ((((size_t)(b * NHEADS + h)) << 6) + d) * SEQ + t0) = v;
            } else {
                const float sc = which == 0 ? qscale : 1.f;
                unsigned short* dst = (which == 0 ? Qo : Ko) +
                    ((((size_t)(b * NHEADS + h)) << 11) + t0) * 64 + d;
#pragma unroll
                for (int r = 0; r < 4; ++r)
                    dst[(size_t)r * 64] = f2bf((acc[i][j][r] + bval) * sc);
            }
        }
    }
}

// ---------------------------------------------------------------------------
// Output projection (proven, unchanged)
// ---------------------------------------------------------------------------
__global__ __launch_bounds__(256)
void out_gemm(const unsigned short* __restrict__ aob,
              const unsigned short* __restrict__ Wto,
              const float* __restrict__ bo, float* __restrict__ out)
{
    __shared__ __align__(16) unsigned short As[128 * 64];
    __shared__ __align__(16) unsigned short Bs[64 * 64];
    const int tid = threadIdx.x, wv = tid >> 6, lane = tid & 63;
    const int m16 = lane & 15, quad = lane >> 4;
    const int n0 = blockIdx.x << 6;
    const int bm = blockIdx.y << 7;

    f32x4 acc[4][2];
#pragma unroll
    for (int i = 0; i < 4; ++i)
#pragma unroll
        for (int j = 0; j < 2; ++j) acc[i][j] = (f32x4){0.f, 0.f, 0.f, 0.f};

    mfma_gemm_core64(aob, Wto, bm, n0, As, Bs, wv, lane, acc);

    const int mb = (wv >> 1) << 6, nb = (wv & 1) << 5;
#pragma unroll
    for (int i = 0; i < 4; ++i) {
        const int m0 = bm + mb + i * 16 + quad * 4;
#pragma unroll
        for (int j = 0; j < 2; ++j) {
            const int n = n0 + nb + j * 16 + m16;
            const float bval = bo[n];
#pragma unroll
            for (int r = 0; r < 4; ++r)
                out[(size_t)(m0 + r) * EMBED + n] = acc[i][j][r] + bval;
        }
    }
}

// ---------------------------------------------------------------------------
// MFMA flash attention v7 (operand-swapped, round-4-proven skeleton).
// Block = 2 waves (128 thr) = 64 queries; each WAVE owns 32 queries as TWO
// 16-query B-fragments, so every K/V LDS fragment read feeds 2 MFMAs
// (halves LDS traffic per query vs round 4). K/V staged to LDS via register
// prefetch + single barrier/iter + ping-pong buffers (round-4 scheme).
// P handoff: wave-local LDS, f2bf + us4 stores, bf16x8 reads, NO barrier
// (round-4-proven). Grid (32,32)=1024 blocks heavy-first; LDS 45KB -> 3
// blocks/CU resident + backfill.
// ---------------------------------------------------------------------------
__global__ __launch_bounds__(128)
void attn_mfma(const unsigned short* __restrict__ Qb,
               const unsigned short* __restrict__ Kb,
               const unsigned short* __restrict__ Vtb,
               unsigned short* __restrict__ Oout)
{
    __shared__ __align__(16) unsigned short Kst[2][64 * 72];   // [key][d]
    __shared__ __align__(16) unsigned short Vst[2][64 * 72];   // [d][key]
    __shared__ __align__(16) unsigned short Ps[2][2][16 * 72]; // [wave][qg][q][key]

    const int tid  = threadIdx.x;
    const int w    = tid >> 6;
    const int lane = tid & 63;
    const int m16  = lane & 15;
    const int quad = lane >> 4;
    const int bh   = blockIdx.y;
    const int b    = bh >> 4, h = bh & 15;
    const int qs   = 31 - (int)blockIdx.x;   // 64-query tile, heavy first

    const int srow  = tid >> 1;        // 0..63
    const int shalf = (tid & 1) << 5;  // 0 or 32 shorts

    // Q fragments (B operand), 2 query groups per wave
    bf16x8 qa0[2], qa1[2];
#pragma unroll
    for (int qg = 0; qg < 2; ++qg) {
        const unsigned short* qp = Qb +
            (((size_t)bh << 11) + (qs << 6) + (w << 5) + (qg << 4) + m16) * 64 + (quad << 3);
        qa0[qg] = *(const bf16x8*)qp;
        qa1[qg] = *(const bf16x8*)(qp + 32);
    }

    const unsigned short* Kbase = Kb + (((size_t)bh << 11) << 6);   // [t][d]
    const unsigned short* Vbase = Vtb + (((size_t)bh << 6) << 11);  // [d][t]

    bf16x8 rk[4], rv[4];
    auto load_tile = [&](int k0) {
        const unsigned short* gk = Kbase + (size_t)(k0 + srow) * 64 + shalf;
        const unsigned short* gv = Vbase + (size_t)srow * SEQ + k0 + shalf;
#pragma unroll
        for (int j = 0; j < 4; ++j) {
            rk[j] = *(const bf16x8*)(gk + j * 8);
            rv[j] = *(const bf16x8*)(gv + j * 8);
        }
    };

    f32x4 o[2][4];
#pragma unroll
    for (int qg = 0; qg < 2; ++qg)
#pragma unroll
        for (int dt = 0; dt < 4; ++dt) o[qg][dt] = (f32x4){0.f, 0.f, 0.f, 0.f};
    float m_[2] = {-1e30f, -1e30f}, l_[2] = {0.f, 0.f};

    load_tile(0);

    for (int kt = 0; kt <= qs; ++kt) {
        unsigned short* Kp = Kst[kt & 1];
        unsigned short* Vp = Vst[kt & 1];
#pragma unroll
        for (int j = 0; j < 4; ++j) {
            *(bf16x8*)(Kp + srow * 72 + shalf + j * 8) = rk[j];
            *(bf16x8*)(Vp + srow * 72 + shalf + j * 8) = rv[j];
        }
        __syncthreads();
        if (kt < qs) load_tile((kt + 1) << 6);

        const bool diag = (kt == qs);

        // K fragments read ONCE, shared by both query groups
        bf16x8 kb0[4], kb1[4];
#pragma unroll
        for (int g = 0; g < 4; ++g) {
            const unsigned short* kp = Kp + (g * 16 + m16) * 72 + (quad << 3);
            kb0[g] = *(const bf16x8*)kp;
            kb1[g] = *(const bf16x8*)(kp + 32);
        }

#pragma unroll
        for (int qg = 0; qg < 2; ++qg) {
            const int gcut = (w << 1) + qg;   // diag: groups > gcut fully masked
            f32x4 s[4];
#pragma unroll
            for (int g = 0; g < 4; ++g) {
                if (diag && g > gcut) {
                    s[g] = (f32x4){-1e30f, -1e30f, -1e30f, -1e30f};
                    continue;
                }
                s[g] = (f32x4){0.f, 0.f, 0.f, 0.f};
                s[g] = __builtin_amdgcn_mfma_f32_16x16x32_bf16(kb0[g], qa0[qg], s[g], 0, 0, 0);
                s[g] = __builtin_amdgcn_mfma_f32_16x16x32_bf16(kb1[g], qa1[qg], s[g], 0, 0, 0);
            }
            if (diag) {   // partial mask on group gcut
#pragma unroll
                for (int r = 0; r < 4; ++r)
                    if (quad * 4 + r > m16) s[gcut][r] = -1e30f;
            }

            // online softmax (all 16 values belong to query m16 of this qg)
            f32x4 t01, t23, tm;
#pragma unroll
            for (int r = 0; r < 4; ++r) {
                t01[r] = fmaxf(s[0][r], s[1][r]);
                t23[r] = fmaxf(s[2][r], s[3][r]);
                tm[r]  = fmaxf(t01[r], t23[r]);
            }
            float mx = fmaxf(fmaxf(tm[0], tm[1]), fmaxf(tm[2], tm[3]));
            mx = fmaxf(mx, __shfl_xor(mx, 16));
            mx = fmaxf(mx, __shfl_xor(mx, 32));
            const float nm = fmaxf(m_[qg], mx);
            const float alpha = exp2f(m_[qg] - nm);
#pragma unroll
            for (int g = 0; g < 4; ++g)
#pragma unroll
                for (int r = 0; r < 4; ++r) s[g][r] = exp2f(s[g][r] - nm);
            f32x4 a01, a23, at;
#pragma unroll
            for (int r = 0; r < 4; ++r) {
                a01[r] = s[0][r] + s[1][r];
                a23[r] = s[2][r] + s[3][r];
                at[r]  = a01[r] + a23[r];
            }
            float sum = (at[0] + at[1]) + (at[2] + at[3]);
            sum += __shfl_xor(sum, 16);
            sum += __shfl_xor(sum, 32);
            l_[qg] = l_[qg] * alpha + sum;
            m_[qg] = nm;

            // P -> LDS (round-4-proven types: f2bf + us4 stores, wave-local)
#pragma unroll
            for (int g = 0; g < 4; ++g) {
                us4 pv;
#pragma unroll
                for (int r = 0; r < 4; ++r) pv[r] = f2bf(s[g][r]);
                *(us4*)(&Ps[w][qg][m16 * 72 + g * 16 + quad * 4]) = pv;
            }
#pragma unroll
            for (int dt = 0; dt < 4; ++dt) o[qg][dt] *= alpha;
        }

        // P^T fragments (B operand)
        bf16x8 pa0[2], pa1[2];
#pragma unroll
        for (int qg = 0; qg < 2; ++qg) {
            const unsigned short* pp = &Ps[w][qg][m16 * 72 + (quad << 3)];
            pa0[qg] = *(const bf16x8*)pp;
            pa1[qg] = *(const bf16x8*)(pp + 32);
        }

        // O^T += V^T · P^T ; V fragments read ONCE, feed both query groups
        const bool skip_hi = diag && (w == 0);   // keys 32..63 masked for both qg
#pragma unroll
        for (int dt = 0; dt < 4; ++dt) {
            const unsigned short* vp = Vp + (dt * 16 + m16) * 72 + (quad << 3);
            bf16x8 vb0 = *(const bf16x8*)vp;
            o[0][dt] = __builtin_amdgcn_mfma_f32_16x16x32_bf16(vb0, pa0[0], o[0][dt], 0, 0, 0);
            o[1][dt] = __builtin_amdgcn_mfma_f32_16x16x32_bf16(vb0, pa0[1], o[1][dt], 0, 0, 0);
            if (!skip_hi) {
                bf16x8 vb1 = *(const bf16x8*)(vp + 32);
                o[0][dt] = __builtin_amdgcn_mfma_f32_16x16x32_bf16(vb1, pa1[0], o[0][dt], 0, 0, 0);
                o[1][dt] = __builtin_amdgcn_mfma_f32_16x16x32_bf16(vb1, pa1[1], o[1][dt], 0, 0, 0);
            }
        }
        // no second barrier needed: this iter's K/V reads precede each wave's
        // arrival at next iter's barrier; next writes go to the other buffer.
    }

    // epilogue: query t = qs*64 + w*32 + qg*16 + m16; d = dt*16 + quad*4 + r
#pragma unroll
    for (int qg = 0; qg < 2; ++qg) {
        const float inv = 1.f / l_[qg];
        const int t = (qs << 6) + (w << 5) + (qg << 4) + m16;
        unsigned short* dst =
            Oout + ((size_t)((b << 11) + t) << 10) + (h << 6) + (quad << 2);
#pragma unroll
        for (int dt = 0; dt < 4; ++dt) {
            us4 wv4;
#pragma unroll
            for (int r = 0; r < 4; ++r) wv4[r] = f2bf(o[qg][dt][r] * inv);
            *(us4*)(dst + dt * 16) = wv4;
        }
    }
}

extern "C" void kernel_launch(void* const* d_in, const int* in_sizes, int n_in,
                              void* d_out, int out_size, void* d_ws, size_t ws_size,
                              hipStream_t stream) {
    const float* x  = (const float*)d_in[0];
    const float* Wq = (const float*)d_in[1];
    const float* bq = (const float*)d_in[2];
    const float* Wk = (const float*)d_in[3];
    const float* bk = (const float*)d_in[4];
    const float* Wv = (const float*)d_in[5];
    const float* bv = (const float*)d_in[6];
    const float* Wo = (const float*)d_in[7];
    const float* bo = (const float*)d_in[8];
    float* out = (float*)d_out;

    const size_t HSZ = (size_t)MROWS * EMBED;   // 4M elems
    const size_t WSZ = (size_t)EMBED * EMBED;   // 1M elems
    unsigned short* qb  = (unsigned short*)d_ws;
    unsigned short* kb  = qb + HSZ;
    unsigned short* vtb = kb + HSZ;
    unsigned short* aob = vtb + HSZ;
    unsigned short* xb  = aob + HSZ;
    unsigned short* wtq = xb + HSZ;
    unsigned short* wtk = wtq + WSZ;
    unsigned short* wtv = wtk + WSZ;
    unsigned short* wto = wtv + WSZ;

    cvt_all<<<dim3(1024, 1, 5), 256, 0, stream>>>(x, Wq, Wk, Wv, Wo,
                                                  xb, wtq, wtk, wtv, wto);

    qkv_gemm<<<dim3(24, 32), 256, 0, stream>>>(xb, wtq, wtk, wtv, bq, bk, bv,
                                               qb, kb, vtb);

    attn_mfma<<<dim3(32, BATCH * NHEADS), 128, 0, stream>>>(qb, kb, vtb, aob);

    out_gemm<<<dim3(16, 32), 256, 0, stream>>>(aob, wto, bo, out);
}

// Round 8
// 256.787 us; speedup vs baseline: 1.5299x; 1.1430x over previous
//
#include <hip/hip_runtime.h>

#define EMBED 1024
#define NHEADS 16
#define HDIM 64
#define SEQ 2048
#define BATCH 2
#define MROWS (BATCH * SEQ)   // 4096

using bf16x8 = __attribute__((ext_vector_type(8))) short;
using f32x4  = __attribute__((ext_vector_type(4))) float;
using us4    = __attribute__((ext_vector_type(4))) unsigned short;

__device__ __forceinline__ unsigned short f2bf(float f) {
    unsigned int u = __builtin_bit_cast(unsigned int, f);
    u = (u + 0x7fffu + ((u >> 16) & 1u)) >> 16;   // RNE
    return (unsigned short)u;
}

__device__ __forceinline__ void async16(const unsigned short* g, unsigned short* l) {
    __builtin_amdgcn_global_load_lds(
        (const __attribute__((address_space(1))) void*)g,
        (__attribute__((address_space(3))) void*)l, 16, 0, 0);
}

// ---------------------------------------------------------------------------
// Merged conversion kernel. grid (1024, 1, 5).
// ---------------------------------------------------------------------------
__global__ __launch_bounds__(256)
void cvt_all(const float* __restrict__ x,
             const float* __restrict__ W1, const float* __restrict__ W2,
             const float* __restrict__ W3, const float* __restrict__ W4,
             unsigned short* __restrict__ xb,
             unsigned short* __restrict__ T1, unsigned short* __restrict__ T2,
             unsigned short* __restrict__ T3, unsigned short* __restrict__ T4)
{
    const int tid = threadIdx.x;
    const int z = blockIdx.z;
    if (z == 0) {
        int base = blockIdx.x * 1024 + tid;
#pragma unroll
        for (int j = 0; j < 4; ++j) {
            int i = base + j * 256;
            float4 v = ((const float4*)x)[i];
            us4 o;
            o[0] = f2bf(v.x); o[1] = f2bf(v.y); o[2] = f2bf(v.z); o[3] = f2bf(v.w);
            ((us4*)xb)[i] = o;
        }
        return;
    }
    if (blockIdx.x >= 256) return;
    const float* W = z == 1 ? W1 : z == 2 ? W2 : z == 3 ? W3 : W4;
    unsigned short* T = z == 1 ? T1 : z == 2 ? T2 : z == 3 ? T3 : T4;
    __shared__ unsigned short tile[64][72];
    const int k0 = (blockIdx.x >> 4) << 6, n0 = (blockIdx.x & 15) << 6;
    const int lr = tid >> 4, lc = (tid & 15) << 2;
#pragma unroll
    for (int it = 0; it < 4; ++it) {
        int kr = lr + it * 16;
        float4 v = *(const float4*)(W + (size_t)(k0 + kr) * EMBED + n0 + lc);
        tile[lc + 0][kr] = f2bf(v.x);
        tile[lc + 1][kr] = f2bf(v.y);
        tile[lc + 2][kr] = f2bf(v.z);
        tile[lc + 3][kr] = f2bf(v.w);
    }
    __syncthreads();
#pragma unroll
    for (int it = 0; it < 4; ++it) {
        int nr = lr + it * 16;
        us4 o = *(const us4*)(&tile[nr][lc]);
        *(us4*)(T + (size_t)(n0 + nr) * EMBED + k0 + lc) = o;
    }
}

// ---------------------------------------------------------------------------
// MFMA GEMM core 128x128 (proven, unchanged)
// ---------------------------------------------------------------------------
__device__ __forceinline__ void mfma_gemm_core(
    const unsigned short* __restrict__ A, const unsigned short* __restrict__ Bt,
    int bm, int n0, unsigned short* As, unsigned short* Bs,
    int wv, int lane, f32x4 acc[4][4])
{
    const int m16 = lane & 15, quad = lane >> 4;
    const int mb = (wv >> 1) << 6;
    const int nb = (wv & 1) << 6;

    const unsigned short* ga = A  + (size_t)(bm + wv * 32 + (lane >> 3)) * EMBED + ((lane & 7) << 3);
    const unsigned short* gb = Bt + (size_t)(n0 + wv * 32 + (lane >> 3)) * EMBED + ((lane & 7) << 3);
    unsigned short* la = As + wv * 32 * 64;
    unsigned short* lb = Bs + wv * 32 * 64;

    for (int k0 = 0; k0 < EMBED; k0 += 64) {
        __syncthreads();
#pragma unroll
        for (int j = 0; j < 4; ++j) {
            async16(ga + j * 8 * EMBED, la + j * 8 * 64);
            async16(gb + j * 8 * EMBED, lb + j * 8 * 64);
        }
        ga += 64; gb += 64;
        __syncthreads();
#pragma unroll
        for (int ks = 0; ks < 2; ++ks) {
            const int ko = ks * 32 + (quad << 3);
            bf16x8 af[4], bfv[4];
#pragma unroll
            for (int i = 0; i < 4; ++i) {
                af[i]  = *(const bf16x8*)(As + (mb + i * 16 + m16) * 64 + ko);
                bfv[i] = *(const bf16x8*)(Bs + (nb + i * 16 + m16) * 64 + ko);
            }
#pragma unroll
            for (int i = 0; i < 4; ++i)
#pragma unroll
                for (int j = 0; j < 4; ++j)
                    acc[i][j] = __builtin_amdgcn_mfma_f32_16x16x32_bf16(
                        af[i], bfv[j], acc[i][j], 0, 0, 0);
        }
    }
}

// ---------------------------------------------------------------------------
// MFMA GEMM core 128x64 (proven, unchanged)
// ---------------------------------------------------------------------------
__device__ __forceinline__ void mfma_gemm_core64(
    const unsigned short* __restrict__ A, const unsigned short* __restrict__ Bt,
    int bm, int n0, unsigned short* As, unsigned short* Bs,
    int wv, int lane, f32x4 acc[4][2])
{
    const int m16 = lane & 15, quad = lane >> 4;
    const int mb = (wv >> 1) << 6;
    const int nb = (wv & 1) << 5;

    const unsigned short* ga = A  + (size_t)(bm + wv * 32 + (lane >> 3)) * EMBED + ((lane & 7) << 3);
    const unsigned short* gb = Bt + (size_t)(n0 + wv * 16 + (lane >> 3)) * EMBED + ((lane & 7) << 3);
    unsigned short* la = As + wv * 32 * 64;
    unsigned short* lb = Bs + wv * 16 * 64;

    for (int k0 = 0; k0 < EMBED; k0 += 64) {
        __syncthreads();
#pragma unroll
        for (int j = 0; j < 4; ++j)
            async16(ga + j * 8 * EMBED, la + j * 8 * 64);
#pragma unroll
        for (int j = 0; j < 2; ++j)
            async16(gb + j * 8 * EMBED, lb + j * 8 * 64);
        ga += 64; gb += 64;
        __syncthreads();
#pragma unroll
        for (int ks = 0; ks < 2; ++ks) {
            const int ko = ks * 32 + (quad << 3);
            bf16x8 af[4], bfv[2];
#pragma unroll
            for (int i = 0; i < 4; ++i)
                af[i] = *(const bf16x8*)(As + (mb + i * 16 + m16) * 64 + ko);
#pragma unroll
            for (int j = 0; j < 2; ++j)
                bfv[j] = *(const bf16x8*)(Bs + (nb + j * 16 + m16) * 64 + ko);
#pragma unroll
            for (int i = 0; i < 4; ++i)
#pragma unroll
                for (int j = 0; j < 2; ++j)
                    acc[i][j] = __builtin_amdgcn_mfma_f32_16x16x32_bf16(
                        af[i], bfv[j], acc[i][j], 0, 0, 0);
        }
    }
}

// ---------------------------------------------------------------------------
// Fused QKV projection (proven, unchanged)
// ---------------------------------------------------------------------------
__global__ __launch_bounds__(256)
void qkv_gemm(const unsigned short* __restrict__ xb,
              const unsigned short* __restrict__ Wtq,
              const unsigned short* __restrict__ Wtk,
              const unsigned short* __restrict__ Wtv,
              const float* __restrict__ bq, const float* __restrict__ bk,
              const float* __restrict__ bv,
              unsigned short* __restrict__ Qo, unsigned short* __restrict__ Ko,
              unsigned short* __restrict__ Vto)
{
    __shared__ __align__(16) unsigned short As[128 * 64];
    __shared__ __align__(16) unsigned short Bs[128 * 64];
    const int tid = threadIdx.x, wv = tid >> 6, lane = tid & 63;
    const int m16 = lane & 15, quad = lane >> 4;
    const int which = blockIdx.x >> 3;
    const int n0 = (blockIdx.x & 7) << 7;
    const int bm = blockIdx.y << 7;
    const unsigned short* Bt = which == 0 ? Wtq : which == 1 ? Wtk : Wtv;
    const float* bias = which == 0 ? bq : which == 1 ? bk : bv;

    f32x4 acc[4][4];
#pragma unroll
    for (int i = 0; i < 4; ++i)
#pragma unroll
        for (int j = 0; j < 4; ++j) acc[i][j] = (f32x4){0.f, 0.f, 0.f, 0.f};

    mfma_gemm_core(xb, Bt, bm, n0, As, Bs, wv, lane, acc);

    const int mb = (wv >> 1) << 6, nb = (wv & 1) << 6;
    const float qscale = 0.125f * 1.4426950408889634f;
#pragma unroll
    for (int i = 0; i < 4; ++i) {
        const int m0 = bm + mb + i * 16 + quad * 4;
        const int b = m0 >> 11, t0 = m0 & (SEQ - 1);
#pragma unroll
        for (int j = 0; j < 4; ++j) {
            const int n = n0 + nb + j * 16 + m16;
            const int h = n >> 6, d = n & 63;
            const float bval = bias[n];
            if (which == 2) {
                us4 v;
#pragma unroll
                for (int r = 0; r < 4; ++r) v[r] = f2bf(acc[i][j][r] + bval);
                *(us4*)(Vto + ((((size_t)(b * NHEADS + h)) << 6) + d) * SEQ + t0) = v;
            } else {
                const float sc = which == 0 ? qscale : 1.f;
                unsigned short* dst = (which == 0 ? Qo : Ko) +
                    ((((size_t)(b * NHEADS + h)) << 11) + t0) * 64 + d;
#pragma unroll
                for (int r = 0; r < 4; ++r)
                    dst[(size_t)r * 64] = f2bf((acc[i][j][r] + bval) * sc);
            }
        }
    }
}

// ---------------------------------------------------------------------------
// Output projection (proven, unchanged)
// ---------------------------------------------------------------------------
__global__ __launch_bounds__(256)
void out_gemm(const unsigned short* __restrict__ aob,
              const unsigned short* __restrict__ Wto,
              const float* __restrict__ bo, float* __restrict__ out)
{
    __shared__ __align__(16) unsigned short As[128 * 64];
    __shared__ __align__(16) unsigned short Bs[64 * 64];
    const int tid = threadIdx.x, wv = tid >> 6, lane = tid & 63;
    const int m16 = lane & 15, quad = lane >> 4;
    const int n0 = blockIdx.x << 6;
    const int bm = blockIdx.y << 7;

    f32x4 acc[4][2];
#pragma unroll
    for (int i = 0; i < 4; ++i)
#pragma unroll
        for (int j = 0; j < 2; ++j) acc[i][j] = (f32x4){0.f, 0.f, 0.f, 0.f};

    mfma_gemm_core64(aob, Wto, bm, n0, As, Bs, wv, lane, acc);

    const int mb = (wv >> 1) << 6, nb = (wv & 1) << 5;
#pragma unroll
    for (int i = 0; i < 4; ++i) {
        const int m0 = bm + mb + i * 16 + quad * 4;
#pragma unroll
        for (int j = 0; j < 2; ++j) {
            const int n = n0 + nb + j * 16 + m16;
            const float bval = bo[n];
#pragma unroll
            for (int r = 0; r < 4; ++r)
                out[(size_t)(m0 + r) * EMBED + n] = acc[i][j][r] + bval;
        }
    }
}

// ---------------------------------------------------------------------------
// MFMA flash attention v8: paired-tile PERFECT BALANCE (round-4) + 2 query
// groups per wave (round-7 sharing/ILP). Block = 4 waves = 128 queries.
// Phases process q-tiles {15-bx, bx} (128 rows each) -> every block runs
// exactly 36 key-tile iterations. Grid (8,32)=256 uniform blocks (1/CU).
// K/V staged via register prefetch + single barrier/iter + ping-pong LDS
// (round-4 proven). K/V LDS fragments read once feed both query groups.
// Diagonal: kt==2qt -> waves 0,1 diagonal; kt==2qt+1 -> waves 0,1 fully
// masked (skip compute, keep barriers), waves 2,3 diagonal.
// P handoff: wave-local LDS, f2bf + us4 stores, bf16x8 reads (proven).
// ---------------------------------------------------------------------------
__global__ __launch_bounds__(256)
void attn_mfma(const unsigned short* __restrict__ Qb,
               const unsigned short* __restrict__ Kb,
               const unsigned short* __restrict__ Vtb,
               unsigned short* __restrict__ Oout)
{
    __shared__ __align__(16) unsigned short Kst[2][64 * 72];   // [key][d]
    __shared__ __align__(16) unsigned short Vst[2][64 * 72];   // [d][key]
    __shared__ __align__(16) unsigned short Ps[4][2][16 * 72]; // [wave][qg][q][key]

    const int tid  = threadIdx.x;
    const int w    = tid >> 6;
    const int lane = tid & 63;
    const int m16  = lane & 15;
    const int quad = lane >> 4;
    const int bh   = blockIdx.y;
    const int b    = bh >> 4, h = bh & 15;

    const int srow = tid >> 2;         // 0..63
    const int scol = (tid & 3) << 4;   // 0,16,32,48

    const unsigned short* Kbase = Kb + (((size_t)bh << 11) << 6);   // [t][d]
    const unsigned short* Vbase = Vtb + (((size_t)bh << 6) << 11);  // [d][t]

    bf16x8 rk0, rk1, rv0, rv1;
    auto load_tile = [&](int k0) {
        const unsigned short* gk = Kbase + (size_t)(k0 + srow) * 64 + scol;
        rk0 = *(const bf16x8*)gk;
        rk1 = *(const bf16x8*)(gk + 8);
        const unsigned short* gv = Vbase + (size_t)srow * SEQ + k0 + scol;
        rv0 = *(const bf16x8*)gv;
        rv1 = *(const bf16x8*)(gv + 8);
    };

    for (int phase = 0; phase < 2; ++phase) {
        const int qt  = phase ? (int)blockIdx.x : 15 - (int)blockIdx.x;
        const int q0  = qt << 7;           // 128-row query tile base
        const int nkt = 2 * qt + 1;        // last key-tile index (inclusive)

        // Q fragments (B operand): query = q0 + w*32 + qg*16 + m16
        bf16x8 qa0[2], qa1[2];
#pragma unroll
        for (int qg = 0; qg < 2; ++qg) {
            const unsigned short* qp = Qb +
                (((size_t)bh << 11) + q0 + (w << 5) + (qg << 4) + m16) * 64 + (quad << 3);
            qa0[qg] = *(const bf16x8*)qp;
            qa1[qg] = *(const bf16x8*)(qp + 32);
        }

        f32x4 o[2][4];
#pragma unroll
        for (int qg = 0; qg < 2; ++qg)
#pragma unroll
            for (int dt = 0; dt < 4; ++dt) o[qg][dt] = (f32x4){0.f, 0.f, 0.f, 0.f};
        float m_[2] = {-1e30f, -1e30f}, l_[2] = {0.f, 0.f};

        load_tile(0);
        __syncthreads();   // protect ping-pong buffers across phases

        for (int kt = 0; kt <= nkt; ++kt) {
            unsigned short* Kp = Kst[kt & 1];
            unsigned short* Vp = Vst[kt & 1];
            *(bf16x8*)(Kp + srow * 72 + scol)     = rk0;
            *(bf16x8*)(Kp + srow * 72 + scol + 8) = rk1;
            *(bf16x8*)(Vp + srow * 72 + scol)     = rv0;
            *(bf16x8*)(Vp + srow * 72 + scol + 8) = rv1;
            __syncthreads();
            if (kt < nkt) load_tile((kt + 1) << 6);

            // dstate: -1 interior, 0 first diagonal tile (kt==2qt, waves 0,1
            // diagonal), 1 second diagonal tile (kt==2qt+1, waves 0,1 fully
            // masked, waves 2,3 diagonal)
            const int dstate = (kt == nkt - 1) ? 0 : (kt == nkt ? 1 : -1);
            const bool skipwave = (dstate == 1) && (w < 2);
            if (!skipwave) {
                const bool diagw = (dstate == 0) ? (w < 2) : (dstate == 1);
                const int  wloc  = (dstate == 1) ? (w - 2) : w;

                // K fragments read ONCE, shared by both query groups
                bf16x8 kb0[4], kb1[4];
#pragma unroll
                for (int g = 0; g < 4; ++g) {
                    const unsigned short* kp = Kp + (g * 16 + m16) * 72 + (quad << 3);
                    kb0[g] = *(const bf16x8*)kp;
                    kb1[g] = *(const bf16x8*)(kp + 32);
                }

#pragma unroll
                for (int qg = 0; qg < 2; ++qg) {
                    const int gcut = (wloc << 1) + qg;
                    f32x4 s[4];
#pragma unroll
                    for (int g = 0; g < 4; ++g) {
                        if (diagw && g > gcut) {
                            s[g] = (f32x4){-1e30f, -1e30f, -1e30f, -1e30f};
                            continue;
                        }
                        s[g] = (f32x4){0.f, 0.f, 0.f, 0.f};
                        s[g] = __builtin_amdgcn_mfma_f32_16x16x32_bf16(kb0[g], qa0[qg], s[g], 0, 0, 0);
                        s[g] = __builtin_amdgcn_mfma_f32_16x16x32_bf16(kb1[g], qa1[qg], s[g], 0, 0, 0);
                    }
                    if (diagw) {   // partial mask on group gcut
#pragma unroll
                        for (int r = 0; r < 4; ++r)
                            if (quad * 4 + r > m16) s[gcut][r] = -1e30f;
                    }

                    // online softmax (16 in-reg values + 2 cross-quad shuffles)
                    f32x4 t01, t23, tm;
#pragma unroll
                    for (int r = 0; r < 4; ++r) {
                        t01[r] = fmaxf(s[0][r], s[1][r]);
                        t23[r] = fmaxf(s[2][r], s[3][r]);
                        tm[r]  = fmaxf(t01[r], t23[r]);
                    }
                    float mx = fmaxf(fmaxf(tm[0], tm[1]), fmaxf(tm[2], tm[3]));
                    mx = fmaxf(mx, __shfl_xor(mx, 16));
                    mx = fmaxf(mx, __shfl_xor(mx, 32));
                    const float nm = fmaxf(m_[qg], mx);
                    const float alpha = exp2f(m_[qg] - nm);
#pragma unroll
                    for (int g = 0; g < 4; ++g)
#pragma unroll
                        for (int r = 0; r < 4; ++r) s[g][r] = exp2f(s[g][r] - nm);
                    f32x4 a01, a23, at;
#pragma unroll
                    for (int r = 0; r < 4; ++r) {
                        a01[r] = s[0][r] + s[1][r];
                        a23[r] = s[2][r] + s[3][r];
                        at[r]  = a01[r] + a23[r];
                    }
                    float sum = (at[0] + at[1]) + (at[2] + at[3]);
                    sum += __shfl_xor(sum, 16);
                    sum += __shfl_xor(sum, 32);
                    l_[qg] = l_[qg] * alpha + sum;
                    m_[qg] = nm;

                    // P -> LDS (proven: f2bf + us4 stores, wave-local)
#pragma unroll
                    for (int g = 0; g < 4; ++g) {
                        us4 pv;
#pragma unroll
                        for (int r = 0; r < 4; ++r) pv[r] = f2bf(s[g][r]);
                        *(us4*)(&Ps[w][qg][m16 * 72 + g * 16 + quad * 4]) = pv;
                    }
#pragma unroll
                    for (int dt = 0; dt < 4; ++dt) o[qg][dt] *= alpha;
                }

                // P^T fragments (B operand)
                bf16x8 pa0[2], pa1[2];
#pragma unroll
                for (int qg = 0; qg < 2; ++qg) {
                    const unsigned short* pp = &Ps[w][qg][m16 * 72 + (quad << 3)];
                    pa0[qg] = *(const bf16x8*)pp;
                    pa1[qg] = *(const bf16x8*)(pp + 32);
                }

                // O^T += V^T · P^T ; V fragments read ONCE feed both qg
                const bool skip_hi = diagw && (wloc == 0);
#pragma unroll
                for (int dt = 0; dt < 4; ++dt) {
                    const unsigned short* vp = Vp + (dt * 16 + m16) * 72 + (quad << 3);
                    bf16x8 vb0 = *(const bf16x8*)vp;
                    o[0][dt] = __builtin_amdgcn_mfma_f32_16x16x32_bf16(vb0, pa0[0], o[0][dt], 0, 0, 0);
                    o[1][dt] = __builtin_amdgcn_mfma_f32_16x16x32_bf16(vb0, pa0[1], o[1][dt], 0, 0, 0);
                    if (!skip_hi) {
                        bf16x8 vb1 = *(const bf16x8*)(vp + 32);
                        o[0][dt] = __builtin_amdgcn_mfma_f32_16x16x32_bf16(vb1, pa1[0], o[0][dt], 0, 0, 0);
                        o[1][dt] = __builtin_amdgcn_mfma_f32_16x16x32_bf16(vb1, pa1[1], o[1][dt], 0, 0, 0);
                    }
                }
            }
        }

        // epilogue: query t = q0 + w*32 + qg*16 + m16; d = dt*16 + quad*4 + r
#pragma unroll
        for (int qg = 0; qg < 2; ++qg) {
            const float inv = 1.f / l_[qg];
            const int t = q0 + (w << 5) + (qg << 4) + m16;
            unsigned short* dst =
                Oout + ((size_t)((b << 11) + t) << 10) + (h << 6) + (quad << 2);
#pragma unroll
            for (int dt = 0; dt < 4; ++dt) {
                us4 wv4;
#pragma unroll
                for (int r = 0; r < 4; ++r) wv4[r] = f2bf(o[qg][dt][r] * inv);
                *(us4*)(dst + dt * 16) = wv4;
            }
        }
    }
}

extern "C" void kernel_launch(void* const* d_in, const int* in_sizes, int n_in,
                              void* d_out, int out_size, void* d_ws, size_t ws_size,
                              hipStream_t stream) {
    const float* x  = (const float*)d_in[0];
    const float* Wq = (const float*)d_in[1];
    const float* bq = (const float*)d_in[2];
    const float* Wk = (const float*)d_in[3];
    const float* bk = (const float*)d_in[4];
    const float* Wv = (const float*)d_in[5];
    const float* bv = (const float*)d_in[6];
    const float* Wo = (const float*)d_in[7];
    const float* bo = (const float*)d_in[8];
    float* out = (float*)d_out;

    const size_t HSZ = (size_t)MROWS * EMBED;   // 4M elems
    const size_t WSZ = (size_t)EMBED * EMBED;   // 1M elems
    unsigned short* qb  = (unsigned short*)d_ws;
    unsigned short* kb  = qb + HSZ;
    unsigned short* vtb = kb + HSZ;
    unsigned short* aob = vtb + HSZ;
    unsigned short* xb  = aob + HSZ;
    unsigned short* wtq = xb + HSZ;
    unsigned short* wtk = wtq + WSZ;
    unsigned short* wtv = wtk + WSZ;
    unsigned short* wto = wtv + WSZ;

    cvt_all<<<dim3(1024, 1, 5), 256, 0, stream>>>(x, Wq, Wk, Wv, Wo,
                                                  xb, wtq, wtk, wtv, wto);

    qkv_gemm<<<dim3(24, 32), 256, 0, stream>>>(xb, wtq, wtk, wtv, bq, bk, bv,
                                               qb, kb, vtb);

    attn_mfma<<<dim3(8, BATCH * NHEADS), 256, 0, stream>>>(qb, kb, vtb, aob);

    out_gemm<<<dim3(16, 32), 256, 0, stream>>>(aob, wto, bo, out);
}

// Round 9
// 242.438 us; speedup vs baseline: 1.6204x; 1.0592x over previous
//
#include <hip/hip_runtime.h>

#define EMBED 1024
#define NHEADS 16
#define HDIM 64
#define SEQ 2048
#define BATCH 2
#define MROWS (BATCH * SEQ)   // 4096

using bf16x8 = __attribute__((ext_vector_type(8))) short;
using f32x4  = __attribute__((ext_vector_type(4))) float;
using us4    = __attribute__((ext_vector_type(4))) unsigned short;

__device__ __forceinline__ unsigned short f2bf(float f) {
    unsigned int u = __builtin_bit_cast(unsigned int, f);
    u = (u + 0x7fffu + ((u >> 16) & 1u)) >> 16;   // RNE
    return (unsigned short)u;
}

__device__ __forceinline__ void async16(const unsigned short* g, unsigned short* l) {
    __builtin_amdgcn_global_load_lds(
        (const __attribute__((address_space(1))) void*)g,
        (__attribute__((address_space(3))) void*)l, 16, 0, 0);
}

// ---------------------------------------------------------------------------
// Merged conversion kernel. grid (1024, 1, 5).
// ---------------------------------------------------------------------------
__global__ __launch_bounds__(256)
void cvt_all(const float* __restrict__ x,
             const float* __restrict__ W1, const float* __restrict__ W2,
             const float* __restrict__ W3, const float* __restrict__ W4,
             unsigned short* __restrict__ xb,
             unsigned short* __restrict__ T1, unsigned short* __restrict__ T2,
             unsigned short* __restrict__ T3, unsigned short* __restrict__ T4)
{
    const int tid = threadIdx.x;
    const int z = blockIdx.z;
    if (z == 0) {
        int base = blockIdx.x * 1024 + tid;
#pragma unroll
        for (int j = 0; j < 4; ++j) {
            int i = base + j * 256;
            float4 v = ((const float4*)x)[i];
            us4 o;
            o[0] = f2bf(v.x); o[1] = f2bf(v.y); o[2] = f2bf(v.z); o[3] = f2bf(v.w);
            ((us4*)xb)[i] = o;
        }
        return;
    }
    if (blockIdx.x >= 256) return;
    const float* W = z == 1 ? W1 : z == 2 ? W2 : z == 3 ? W3 : W4;
    unsigned short* T = z == 1 ? T1 : z == 2 ? T2 : z == 3 ? T3 : T4;
    __shared__ unsigned short tile[64][72];
    const int k0 = (blockIdx.x >> 4) << 6, n0 = (blockIdx.x & 15) << 6;
    const int lr = tid >> 4, lc = (tid & 15) << 2;
#pragma unroll
    for (int it = 0; it < 4; ++it) {
        int kr = lr + it * 16;
        float4 v = *(const float4*)(W + (size_t)(k0 + kr) * EMBED + n0 + lc);
        tile[lc + 0][kr] = f2bf(v.x);
        tile[lc + 1][kr] = f2bf(v.y);
        tile[lc + 2][kr] = f2bf(v.z);
        tile[lc + 3][kr] = f2bf(v.w);
    }
    __syncthreads();
#pragma unroll
    for (int it = 0; it < 4; ++it) {
        int nr = lr + it * 16;
        us4 o = *(const us4*)(&tile[nr][lc]);
        *(us4*)(T + (size_t)(n0 + nr) * EMBED + k0 + lc) = o;
    }
}

// ---------------------------------------------------------------------------
// MFMA GEMM core 128x128 (proven, unchanged)
// ---------------------------------------------------------------------------
__device__ __forceinline__ void mfma_gemm_core(
    const unsigned short* __restrict__ A, const unsigned short* __restrict__ Bt,
    int bm, int n0, unsigned short* As, unsigned short* Bs,
    int wv, int lane, f32x4 acc[4][4])
{
    const int m16 = lane & 15, quad = lane >> 4;
    const int mb = (wv >> 1) << 6;
    const int nb = (wv & 1) << 6;

    const unsigned short* ga = A  + (size_t)(bm + wv * 32 + (lane >> 3)) * EMBED + ((lane & 7) << 3);
    const unsigned short* gb = Bt + (size_t)(n0 + wv * 32 + (lane >> 3)) * EMBED + ((lane & 7) << 3);
    unsigned short* la = As + wv * 32 * 64;
    unsigned short* lb = Bs + wv * 32 * 64;

    for (int k0 = 0; k0 < EMBED; k0 += 64) {
        __syncthreads();
#pragma unroll
        for (int j = 0; j < 4; ++j) {
            async16(ga + j * 8 * EMBED, la + j * 8 * 64);
            async16(gb + j * 8 * EMBED, lb + j * 8 * 64);
        }
        ga += 64; gb += 64;
        __syncthreads();
#pragma unroll
        for (int ks = 0; ks < 2; ++ks) {
            const int ko = ks * 32 + (quad << 3);
            bf16x8 af[4], bfv[4];
#pragma unroll
            for (int i = 0; i < 4; ++i) {
                af[i]  = *(const bf16x8*)(As + (mb + i * 16 + m16) * 64 + ko);
                bfv[i] = *(const bf16x8*)(Bs + (nb + i * 16 + m16) * 64 + ko);
            }
#pragma unroll
            for (int i = 0; i < 4; ++i)
#pragma unroll
                for (int j = 0; j < 4; ++j)
                    acc[i][j] = __builtin_amdgcn_mfma_f32_16x16x32_bf16(
                        af[i], bfv[j], acc[i][j], 0, 0, 0);
        }
    }
}

// ---------------------------------------------------------------------------
// MFMA GEMM core 128x64 (proven, unchanged)
// ---------------------------------------------------------------------------
__device__ __forceinline__ void mfma_gemm_core64(
    const unsigned short* __restrict__ A, const unsigned short* __restrict__ Bt,
    int bm, int n0, unsigned short* As, unsigned short* Bs,
    int wv, int lane, f32x4 acc[4][2])
{
    const int m16 = lane & 15, quad = lane >> 4;
    const int mb = (wv >> 1) << 6;
    const int nb = (wv & 1) << 5;

    const unsigned short* ga = A  + (size_t)(bm + wv * 32 + (lane >> 3)) * EMBED + ((lane & 7) << 3);
    const unsigned short* gb = Bt + (size_t)(n0 + wv * 16 + (lane >> 3)) * EMBED + ((lane & 7) << 3);
    unsigned short* la = As + wv * 32 * 64;
    unsigned short* lb = Bs + wv * 16 * 64;

    for (int k0 = 0; k0 < EMBED; k0 += 64) {
        __syncthreads();
#pragma unroll
        for (int j = 0; j < 4; ++j)
            async16(ga + j * 8 * EMBED, la + j * 8 * 64);
#pragma unroll
        for (int j = 0; j < 2; ++j)
            async16(gb + j * 8 * EMBED, lb + j * 8 * 64);
        ga += 64; gb += 64;
        __syncthreads();
#pragma unroll
        for (int ks = 0; ks < 2; ++ks) {
            const int ko = ks * 32 + (quad << 3);
            bf16x8 af[4], bfv[2];
#pragma unroll
            for (int i = 0; i < 4; ++i)
                af[i] = *(const bf16x8*)(As + (mb + i * 16 + m16) * 64 + ko);
#pragma unroll
            for (int j = 0; j < 2; ++j)
                bfv[j] = *(const bf16x8*)(Bs + (nb + j * 16 + m16) * 64 + ko);
#pragma unroll
            for (int i = 0; i < 4; ++i)
#pragma unroll
                for (int j = 0; j < 2; ++j)
                    acc[i][j] = __builtin_amdgcn_mfma_f32_16x16x32_bf16(
                        af[i], bfv[j], acc[i][j], 0, 0, 0);
        }
    }
}

// ---------------------------------------------------------------------------
// Fused QKV projection (proven, unchanged)
// ---------------------------------------------------------------------------
__global__ __launch_bounds__(256)
void qkv_gemm(const unsigned short* __restrict__ xb,
              const unsigned short* __restrict__ Wtq,
              const unsigned short* __restrict__ Wtk,
              const unsigned short* __restrict__ Wtv,
              const float* __restrict__ bq, const float* __restrict__ bk,
              const float* __restrict__ bv,
              unsigned short* __restrict__ Qo, unsigned short* __restrict__ Ko,
              unsigned short* __restrict__ Vto)
{
    __shared__ __align__(16) unsigned short As[128 * 64];
    __shared__ __align__(16) unsigned short Bs[128 * 64];
    const int tid = threadIdx.x, wv = tid >> 6, lane = tid & 63;
    const int m16 = lane & 15, quad = lane >> 4;
    const int which = blockIdx.x >> 3;
    const int n0 = (blockIdx.x & 7) << 7;
    const int bm = blockIdx.y << 7;
    const unsigned short* Bt = which == 0 ? Wtq : which == 1 ? Wtk : Wtv;
    const float* bias = which == 0 ? bq : which == 1 ? bk : bv;

    f32x4 acc[4][4];
#pragma unroll
    for (int i = 0; i < 4; ++i)
#pragma unroll
        for (int j = 0; j < 4; ++j) acc[i][j] = (f32x4){0.f, 0.f, 0.f, 0.f};

    mfma_gemm_core(xb, Bt, bm, n0, As, Bs, wv, lane, acc);

    const int mb = (wv >> 1) << 6, nb = (wv & 1) << 6;
    const float qscale = 0.125f * 1.4426950408889634f;
#pragma unroll
    for (int i = 0; i < 4; ++i) {
        const int m0 = bm + mb + i * 16 + quad * 4;
        const int b = m0 >> 11, t0 = m0 & (SEQ - 1);
#pragma unroll
        for (int j = 0; j < 4; ++j) {
            const int n = n0 + nb + j * 16 + m16;
            const int h = n >> 6, d = n & 63;
            const float bval = bias[n];
            if (which == 2) {
                us4 v;
#pragma unroll
                for (int r = 0; r < 4; ++r) v[r] = f2bf(acc[i][j][r] + bval);
                *(us4*)(Vto + ((((size_t)(b * NHEADS + h)) << 6) + d) * SEQ + t0) = v;
            } else {
                const float sc = which == 0 ? qscale : 1.f;
                unsigned short* dst = (which == 0 ? Qo : Ko) +
                    ((((size_t)(b * NHEADS + h)) << 11) + t0) * 64 + d;
#pragma unroll
                for (int r = 0; r < 4; ++r)
                    dst[(size_t)r * 64] = f2bf((acc[i][j][r] + bval) * sc);
            }
        }
    }
}

// ---------------------------------------------------------------------------
// Output projection (proven, unchanged)
// ---------------------------------------------------------------------------
__global__ __launch_bounds__(256)
void out_gemm(const unsigned short* __restrict__ aob,
              const unsigned short* __restrict__ Wto,
              const float* __restrict__ bo, float* __restrict__ out)
{
    __shared__ __align__(16) unsigned short As[128 * 64];
    __shared__ __align__(16) unsigned short Bs[64 * 64];
    const int tid = threadIdx.x, wv = tid >> 6, lane = tid & 63;
    const int m16 = lane & 15, quad = lane >> 4;
    const int n0 = blockIdx.x << 6;
    const int bm = blockIdx.y << 7;

    f32x4 acc[4][2];
#pragma unroll
    for (int i = 0; i < 4; ++i)
#pragma unroll
        for (int j = 0; j < 2; ++j) acc[i][j] = (f32x4){0.f, 0.f, 0.f, 0.f};

    mfma_gemm_core64(aob, Wto, bm, n0, As, Bs, wv, lane, acc);

    const int mb = (wv >> 1) << 6, nb = (wv & 1) << 5;
#pragma unroll
    for (int i = 0; i < 4; ++i) {
        const int m0 = bm + mb + i * 16 + quad * 4;
#pragma unroll
        for (int j = 0; j < 2; ++j) {
            const int n = n0 + nb + j * 16 + m16;
            const float bval = bo[n];
#pragma unroll
            for (int r = 0; r < 4; ++r)
                out[(size_t)(m0 + r) * EMBED + n] = acc[i][j][r] + bval;
        }
    }
}

// ---------------------------------------------------------------------------
// MFMA flash attention v9: round-8 block (4 waves x 2 query-groups = 128
// queries, K/V LDS fragments shared across both qg) but ONE tile per block
// and grid (16,32)=512 -> 2 blocks/CU co-resident (the round-4 overlap that
// round 8 lost). Balance via dispatch-pairing: qt = (bh<16)? bx : 15-bx, so
// blocks id and id+256 (same CU under any CU = g(id mod 256) assignment)
// carry complementary tiles: (2qt+2)+(2(15-qt)+2) = 34 iters per CU.
// LDS 54KB (2 blocks = 108KB <= 160KB). Staging/barrier/P-handoff proven.
// ---------------------------------------------------------------------------
__global__ __launch_bounds__(256)
void attn_mfma(const unsigned short* __restrict__ Qb,
               const unsigned short* __restrict__ Kb,
               const unsigned short* __restrict__ Vtb,
               unsigned short* __restrict__ Oout)
{
    __shared__ __align__(16) unsigned short Kst[2][64 * 72];   // [key][d]
    __shared__ __align__(16) unsigned short Vst[2][64 * 72];   // [d][key]
    __shared__ __align__(16) unsigned short Ps[4][2][16 * 72]; // [wave][qg][q][key]

    const int tid  = threadIdx.x;
    const int w    = tid >> 6;
    const int lane = tid & 63;
    const int m16  = lane & 15;
    const int quad = lane >> 4;
    const int bh   = blockIdx.y;
    const int b    = bh >> 4, h = bh & 15;

    // complementary-pair tile mapping: id and id+256 share a CU and get
    // tiles qt and 15-qt -> uniform 34 iters per CU
    const int qt  = (bh < 16) ? (int)blockIdx.x : 15 - (int)blockIdx.x;
    const int q0  = qt << 7;           // 128-row query tile base
    const int nkt = 2 * qt + 1;        // last key-tile index (inclusive)

    const int srow = tid >> 2;         // 0..63
    const int scol = (tid & 3) << 4;   // 0,16,32,48

    const unsigned short* Kbase = Kb + (((size_t)bh << 11) << 6);   // [t][d]
    const unsigned short* Vbase = Vtb + (((size_t)bh << 6) << 11);  // [d][t]

    bf16x8 rk0, rk1, rv0, rv1;
    auto load_tile = [&](int k0) {
        const unsigned short* gk = Kbase + (size_t)(k0 + srow) * 64 + scol;
        rk0 = *(const bf16x8*)gk;
        rk1 = *(const bf16x8*)(gk + 8);
        const unsigned short* gv = Vbase + (size_t)srow * SEQ + k0 + scol;
        rv0 = *(const bf16x8*)gv;
        rv1 = *(const bf16x8*)(gv + 8);
    };

    // Q fragments (B operand): query = q0 + w*32 + qg*16 + m16
    bf16x8 qa0[2], qa1[2];
#pragma unroll
    for (int qg = 0; qg < 2; ++qg) {
        const unsigned short* qp = Qb +
            (((size_t)bh << 11) + q0 + (w << 5) + (qg << 4) + m16) * 64 + (quad << 3);
        qa0[qg] = *(const bf16x8*)qp;
        qa1[qg] = *(const bf16x8*)(qp + 32);
    }

    f32x4 o[2][4];
#pragma unroll
    for (int qg = 0; qg < 2; ++qg)
#pragma unroll
        for (int dt = 0; dt < 4; ++dt) o[qg][dt] = (f32x4){0.f, 0.f, 0.f, 0.f};
    float m_[2] = {-1e30f, -1e30f}, l_[2] = {0.f, 0.f};

    load_tile(0);

    for (int kt = 0; kt <= nkt; ++kt) {
        unsigned short* Kp = Kst[kt & 1];
        unsigned short* Vp = Vst[kt & 1];
        *(bf16x8*)(Kp + srow * 72 + scol)     = rk0;
        *(bf16x8*)(Kp + srow * 72 + scol + 8) = rk1;
        *(bf16x8*)(Vp + srow * 72 + scol)     = rv0;
        *(bf16x8*)(Vp + srow * 72 + scol + 8) = rv1;
        __syncthreads();
        if (kt < nkt) load_tile((kt + 1) << 6);

        // dstate: -1 interior, 0 first diagonal tile (kt==2qt: waves 0,1
        // diagonal), 1 second diagonal tile (kt==2qt+1: waves 0,1 fully
        // masked, waves 2,3 diagonal)
        const int dstate = (kt == nkt - 1) ? 0 : (kt == nkt ? 1 : -1);
        const bool skipwave = (dstate == 1) && (w < 2);
        if (!skipwave) {
            const bool diagw = (dstate == 0) ? (w < 2) : (dstate == 1);
            const int  wloc  = (dstate == 1) ? (w - 2) : w;

            // K fragments read ONCE, shared by both query groups
            bf16x8 kb0[4], kb1[4];
#pragma unroll
            for (int g = 0; g < 4; ++g) {
                const unsigned short* kp = Kp + (g * 16 + m16) * 72 + (quad << 3);
                kb0[g] = *(const bf16x8*)kp;
                kb1[g] = *(const bf16x8*)(kp + 32);
            }

#pragma unroll
            for (int qg = 0; qg < 2; ++qg) {
                const int gcut = (wloc << 1) + qg;
                f32x4 s[4];
#pragma unroll
                for (int g = 0; g < 4; ++g) {
                    if (diagw && g > gcut) {
                        s[g] = (f32x4){-1e30f, -1e30f, -1e30f, -1e30f};
                        continue;
                    }
                    s[g] = (f32x4){0.f, 0.f, 0.f, 0.f};
                    s[g] = __builtin_amdgcn_mfma_f32_16x16x32_bf16(kb0[g], qa0[qg], s[g], 0, 0, 0);
                    s[g] = __builtin_amdgcn_mfma_f32_16x16x32_bf16(kb1[g], qa1[qg], s[g], 0, 0, 0);
                }
                if (diagw) {   // partial mask on group gcut
#pragma unroll
                    for (int r = 0; r < 4; ++r)
                        if (quad * 4 + r > m16) s[gcut][r] = -1e30f;
                }

                // online softmax (16 in-reg values + 2 cross-quad shuffles)
                f32x4 t01, t23, tm;
#pragma unroll
                for (int r = 0; r < 4; ++r) {
                    t01[r] = fmaxf(s[0][r], s[1][r]);
                    t23[r] = fmaxf(s[2][r], s[3][r]);
                    tm[r]  = fmaxf(t01[r], t23[r]);
                }
                float mx = fmaxf(fmaxf(tm[0], tm[1]), fmaxf(tm[2], tm[3]));
                mx = fmaxf(mx, __shfl_xor(mx, 16));
                mx = fmaxf(mx, __shfl_xor(mx, 32));
                const float nm = fmaxf(m_[qg], mx);
                const float alpha = exp2f(m_[qg] - nm);
#pragma unroll
                for (int g = 0; g < 4; ++g)
#pragma unroll
                    for (int r = 0; r < 4; ++r) s[g][r] = exp2f(s[g][r] - nm);
                f32x4 a01, a23, at;
#pragma unroll
                for (int r = 0; r < 4; ++r) {
                    a01[r] = s[0][r] + s[1][r];
                    a23[r] = s[2][r] + s[3][r];
                    at[r]  = a01[r] + a23[r];
                }
                float sum = (at[0] + at[1]) + (at[2] + at[3]);
                sum += __shfl_xor(sum, 16);
                sum += __shfl_xor(sum, 32);
                l_[qg] = l_[qg] * alpha + sum;
                m_[qg] = nm;

                // P -> LDS (proven: f2bf + us4 stores, wave-local)
#pragma unroll
                for (int g = 0; g < 4; ++g) {
                    us4 pv;
#pragma unroll
                    for (int r = 0; r < 4; ++r) pv[r] = f2bf(s[g][r]);
                    *(us4*)(&Ps[w][qg][m16 * 72 + g * 16 + quad * 4]) = pv;
                }
#pragma unroll
                for (int dt = 0; dt < 4; ++dt) o[qg][dt] *= alpha;
            }

            // P^T fragments (B operand)
            bf16x8 pa0[2], pa1[2];
#pragma unroll
            for (int qg = 0; qg < 2; ++qg) {
                const unsigned short* pp = &Ps[w][qg][m16 * 72 + (quad << 3)];
                pa0[qg] = *(const bf16x8*)pp;
                pa1[qg] = *(const bf16x8*)(pp + 32);
            }

            // O^T += V^T · P^T ; V fragments read ONCE feed both qg
            const bool skip_hi = diagw && (wloc == 0);
#pragma unroll
            for (int dt = 0; dt < 4; ++dt) {
                const unsigned short* vp = Vp + (dt * 16 + m16) * 72 + (quad << 3);
                bf16x8 vb0 = *(const bf16x8*)vp;
                o[0][dt] = __builtin_amdgcn_mfma_f32_16x16x32_bf16(vb0, pa0[0], o[0][dt], 0, 0, 0);
                o[1][dt] = __builtin_amdgcn_mfma_f32_16x16x32_bf16(vb0, pa0[1], o[1][dt], 0, 0, 0);
                if (!skip_hi) {
                    bf16x8 vb1 = *(const bf16x8*)(vp + 32);
                    o[0][dt] = __builtin_amdgcn_mfma_f32_16x16x32_bf16(vb1, pa1[0], o[0][dt], 0, 0, 0);
                    o[1][dt] = __builtin_amdgcn_mfma_f32_16x16x32_bf16(vb1, pa1[1], o[1][dt], 0, 0, 0);
                }
            }
        }
    }

    // epilogue: query t = q0 + w*32 + qg*16 + m16; d = dt*16 + quad*4 + r
#pragma unroll
    for (int qg = 0; qg < 2; ++qg) {
        const float inv = 1.f / l_[qg];
        const int t = q0 + (w << 5) + (qg << 4) + m16;
        unsigned short* dst =
            Oout + ((size_t)((b << 11) + t) << 10) + (h << 6) + (quad << 2);
#pragma unroll
        for (int dt = 0; dt < 4; ++dt) {
            us4 wv4;
#pragma unroll
            for (int r = 0; r < 4; ++r) wv4[r] = f2bf(o[qg][dt][r] * inv);
            *(us4*)(dst + dt * 16) = wv4;
        }
    }
}

extern "C" void kernel_launch(void* const* d_in, const int* in_sizes, int n_in,
                              void* d_out, int out_size, void* d_ws, size_t ws_size,
                              hipStream_t stream) {
    const float* x  = (const float*)d_in[0];
    const float* Wq = (const float*)d_in[1];
    const float* bq = (const float*)d_in[2];
    const float* Wk = (const float*)d_in[3];
    const float* bk = (const float*)d_in[4];
    const float* Wv = (const float*)d_in[5];
    const float* bv = (const float*)d_in[6];
    const float* Wo = (const float*)d_in[7];
    const float* bo = (const float*)d_in[8];
    float* out = (float*)d_out;

    const size_t HSZ = (size_t)MROWS * EMBED;   // 4M elems
    const size_t WSZ = (size_t)EMBED * EMBED;   // 1M elems
    unsigned short* qb  = (unsigned short*)d_ws;
    unsigned short* kb  = qb + HSZ;
    unsigned short* vtb = kb + HSZ;
    unsigned short* aob = vtb + HSZ;
    unsigned short* xb  = aob + HSZ;
    unsigned short* wtq = xb + HSZ;
    unsigned short* wtk = wtq + WSZ;
    unsigned short* wtv = wtk + WSZ;
    unsigned short* wto = wtv + WSZ;

    cvt_all<<<dim3(1024, 1, 5), 256, 0, stream>>>(x, Wq, Wk, Wv, Wo,
                                                  xb, wtq, wtk, wtv, wto);

    qkv_gemm<<<dim3(24, 32), 256, 0, stream>>>(xb, wtq, wtk, wtv, bq, bk, bv,
                                               qb, kb, vtb);

    attn_mfma<<<dim3(16, BATCH * NHEADS), 256, 0, stream>>>(qb, kb, vtb, aob);

    out_gemm<<<dim3(16, 32), 256, 0, stream>>>(aob, wto, bo, out);
}